// Round 1
// baseline (1215.642 us; speedup 1.0000x reference)
//
#include <hip/hip_runtime.h>
#include <hip/hip_bf16.h>

// ---------------- problem constants ----------------
#define T_TOK 4096
#define HD    2048
#define NE    64
#define TOPK  8
#define IMID  512
#define N13   1024                 // 2*I
#define NPAIR (T_TOK*TOPK)         // 32768
#define NROWS (NPAIR + T_TOK)      // 36864 (routed pairs + shared rows)
#define MAXTILES 384               // >= sum ceil(cnt_e/128) worst case (352)
#define RSCALE 2.5f

typedef __attribute__((ext_vector_type(8))) __bf16 bf16x8;
typedef __attribute__((ext_vector_type(4))) __bf16 bf16x4;
typedef __attribute__((ext_vector_type(4))) float  f32x4;

// ---------------- init: zero out, logits, counters (every call: graph replays re-accumulate) ----
__global__ __launch_bounds__(256) void init_kernel(float4* __restrict__ out4,
                                                   float4* __restrict__ lg4,
                                                   int* __restrict__ counts,
                                                   int* __restrict__ curs) {
  int gid = blockIdx.x * 256 + threadIdx.x;
  float4 z; z.x = z.y = z.z = z.w = 0.f;
  if (gid < (T_TOK * HD / 4)) out4[gid] = z;
  else                        lg4[gid - T_TOK * HD / 4] = z;   // grid sized exactly
  if (gid < NE + 1) { counts[gid] = 0; curs[gid] = 0; }
}

// ---------------- router logits: [T,E] = hs @ gate_w, k-split x8 with atomic reduce --------
__global__ __launch_bounds__(256) void logits_kernel(const float* __restrict__ hs,
                                                     const float* __restrict__ gw,
                                                     float* __restrict__ logits) {
  __shared__ float hsm[64][64];   // [k][tok] (transposed store: conflict-free both sides)
  __shared__ float gwm[64][64];   // [k][e]
  int tid = threadIdx.x;
  int tb = blockIdx.x * 64;        // 64 tokens per block
  int kbase = blockIdx.y * 256;    // 8 k-splits
  int tok = tid & 63, kq = tid >> 6;
  int tq = (tid & 15) * 4, eq = (tid >> 4) * 4;
  float acc[4][4] = {};
  for (int c = 0; c < 4; ++c) {
    int kb = kbase + c * 64;
#pragma unroll
    for (int it = 0; it < 4; ++it) {
      int k4 = kq * 16 + it * 4;
      float4 f = *(const float4*)&hs[(size_t)(tb + tok) * HD + kb + k4];
      hsm[k4 + 0][tok] = f.x; hsm[k4 + 1][tok] = f.y;
      hsm[k4 + 2][tok] = f.z; hsm[k4 + 3][tok] = f.w;
      int q = tid + it * 256;
      int grow = q >> 4, gc = (q & 15) * 4;
      *(float4*)&gwm[grow][gc] = *(const float4*)&gw[(size_t)(kb + grow) * NE + gc];
    }
    __syncthreads();
#pragma unroll 8
    for (int k = 0; k < 64; ++k) {
      float4 g = *(const float4*)&gwm[k][eq];
      float h0 = hsm[k][tq + 0], h1 = hsm[k][tq + 1];
      float h2 = hsm[k][tq + 2], h3 = hsm[k][tq + 3];
      acc[0][0] += h0 * g.x; acc[0][1] += h0 * g.y; acc[0][2] += h0 * g.z; acc[0][3] += h0 * g.w;
      acc[1][0] += h1 * g.x; acc[1][1] += h1 * g.y; acc[1][2] += h1 * g.z; acc[1][3] += h1 * g.w;
      acc[2][0] += h2 * g.x; acc[2][1] += h2 * g.y; acc[2][2] += h2 * g.z; acc[2][3] += h2 * g.w;
      acc[3][0] += h3 * g.x; acc[3][1] += h3 * g.y; acc[3][2] += h3 * g.z; acc[3][3] += h3 * g.w;
    }
    __syncthreads();
  }
#pragma unroll
  for (int i = 0; i < 4; ++i)
#pragma unroll
    for (int j = 0; j < 4; ++j)
      atomicAdd(&logits[(size_t)(tb + tq + i) * NE + eq + j], acc[i][j]);
}

// ---------------- sigmoid + top-8 per token (1 wave/token), renorm, *2.5 -----------------
__global__ __launch_bounds__(256) void top8_kernel(const float* __restrict__ logits,
                                                   int* __restrict__ topk_id,
                                                   float* __restrict__ pair_w,
                                                   int* __restrict__ counts) {
  int lane = threadIdx.x & 63;
  int t = blockIdx.x * 4 + (threadIdx.x >> 6);
  float v = logits[(size_t)t * NE + lane];
  float s = 1.f / (1.f + __expf(-v));   // sigmoid
  float cur = s, ssum = 0.f;
  int myid = 0; float myw = 0.f;
  for (int k = 0; k < TOPK; ++k) {
    float bv = cur; int bi = lane;
#pragma unroll
    for (int off = 32; off >= 1; off >>= 1) {
      float ov = __shfl_xor(bv, off);
      int   oi = __shfl_xor(bi, off);
      if (ov > bv || (ov == bv && oi < bi)) { bv = ov; bi = oi; }  // tie -> lower idx (lax.top_k)
    }
    ssum += bv;
    if (lane == k) { myid = bi; myw = bv; }
    if (lane == bi) cur = -1.f;
  }
  if (lane < TOPK) {
    topk_id[(size_t)t * TOPK + lane] = myid;
    pair_w[(size_t)t * TOPK + lane] = myw / ssum * RSCALE;
    atomicAdd(&counts[myid], 1);
  }
}

// ---------------- scan: offsets + tile table (expert 64 = shared, 4096 rows) -------------
__global__ void scan_kernel(int* __restrict__ counts, int* __restrict__ offs,
                            int2* __restrict__ tiles) {
  if (threadIdx.x != 0) return;
  counts[NE] = T_TOK;
  int off = 0, tix = 0;
  for (int e = 0; e <= NE; ++e) {
    offs[e] = off;
    int c = counts[e];
    int nt = (c + 127) >> 7;
    for (int i = 0; i < nt; ++i) {
      int rr = c - i * 128; if (rr > 128) rr = 128;
      tiles[tix++] = make_int2(off + i * 128, (e << 16) | rr);
    }
    off += c;
  }
  for (; tix < MAXTILES; ++tix) tiles[tix] = make_int2(0, 0);
}

// ---------------- scatter pairs -> compact per-expert rows -------------------------------
__global__ __launch_bounds__(256) void scatter_kernel(const int* __restrict__ topk_id,
                                                      const float* __restrict__ pair_w,
                                                      const int* __restrict__ offs,
                                                      int* __restrict__ curs,
                                                      int* __restrict__ row_token,
                                                      float* __restrict__ row_w) {
  int p = blockIdx.x * 256 + threadIdx.x;   // grid covers exactly NROWS
  int t, e; float w;
  if (p < NPAIR) { t = p >> 3; e = topk_id[p]; w = pair_w[p]; }
  else           { t = p - NPAIR; e = NE;     w = 1.0f; }
  int dst = offs[e] + atomicAdd(&curs[e], 1);
  row_token[dst] = t;
  row_w[dst] = w;
}

// ---------------- helpers --------------------------------------------------------------
// swizzled byte offset inside a [row][64 bf16 = 128B] LDS tile (G4 XOR swizzle)
__device__ __forceinline__ int swz(int row, int kbyte) {
  return row * 128 + (kbyte ^ ((row & 7) << 4));
}

// stage a 64(k) x 128(n) fp32 tile (row stride ldb) into LDS as [n][64k] bf16, swizzled.
// lanes: bn = (tid&63)*2 consecutive pairs -> fully coalesced float2 loads per k-row.
__device__ __forceinline__ void stageB(const float* __restrict__ p /* = W + k0*ldb + ncol + bn */,
                                       int ldb, __bf16* Bs, int bn, int bq) {
#pragma unroll
  for (int it = 0; it < 4; ++it) {
    int kb = bq * 4 + it * 16;
    float2 f0 = *(const float2*)(p + (size_t)(kb + 0) * ldb);
    float2 f1 = *(const float2*)(p + (size_t)(kb + 1) * ldb);
    float2 f2 = *(const float2*)(p + (size_t)(kb + 2) * ldb);
    float2 f3 = *(const float2*)(p + (size_t)(kb + 3) * ldb);
    bf16x4 c0 = { (__bf16)f0.x, (__bf16)f1.x, (__bf16)f2.x, (__bf16)f3.x };
    bf16x4 c1 = { (__bf16)f0.y, (__bf16)f1.y, (__bf16)f2.y, (__bf16)f3.y };
    *(bf16x4*)&Bs[swz(bn,     kb * 2) >> 1] = c0;
    *(bf16x4*)&Bs[swz(bn + 1, kb * 2) >> 1] = c1;
  }
}

// ---------------- grouped GEMM1: h = silu(x@Wg) * (x@Wu), gathered rows, fused ----------
__global__ __launch_bounds__(256, 2) void gemm1_kernel(const float* __restrict__ hidden,
                                                       const float* __restrict__ w13,
                                                       const float* __restrict__ sw13,
                                                       const int* __restrict__ row_token,
                                                       const int2* __restrict__ tiles,
                                                       __bf16* __restrict__ hbuf) {
  int2 td = tiles[blockIdx.x];
  int rows = td.y & 0xFFFF;
  if (rows == 0) return;
  int e = td.y >> 16, row0 = td.x;
  const float* W = (e < NE) ? (w13 + (size_t)e * (HD * N13)) : sw13;  // [2048][1024]
  int n0 = blockIdx.y * 128;                                          // gate col base; up = +512

  __shared__ __bf16 As[128 * 64];
  __shared__ __bf16 Bgs[128 * 64];
  __shared__ __bf16 Bus[128 * 64];

  int tid = threadIdx.x;
  int lane = tid & 63, wv = tid >> 6, wr = wv >> 1, wc = wv & 1;
  int l15 = lane & 15, lq = lane >> 4;

  int arow = tid >> 1, ahalf = tid & 1;
  int grow = row0 + arow; if (grow > NROWS - 1) grow = NROWS - 1;
  const float* Ap = hidden + (size_t)row_token[grow] * HD + ahalf * 32;

  int bn = (lane) * 2, bq = wv;
  const float* Bgp = W + n0 + bn;
  const float* Bup = W + 512 + n0 + bn;

  f32x4 accg[4][4], accu[4][4];
#pragma unroll
  for (int i = 0; i < 4; ++i)
#pragma unroll
    for (int j = 0; j < 4; ++j) { accg[i][j] = (f32x4)(0.f); accu[i][j] = (f32x4)(0.f); }

  for (int k0 = 0; k0 < HD; k0 += 64) {
    { // stage A (gather + cvt), [row][64k] swizzled
      const float4* src = (const float4*)(Ap + k0);
#pragma unroll
      for (int i = 0; i < 4; ++i) {
        float4 f0 = src[i * 2], f1 = src[i * 2 + 1];
        bf16x8 v = { (__bf16)f0.x, (__bf16)f0.y, (__bf16)f0.z, (__bf16)f0.w,
                     (__bf16)f1.x, (__bf16)f1.y, (__bf16)f1.z, (__bf16)f1.w };
        *(bf16x8*)&As[swz(arow, ahalf * 64 + i * 16) >> 1] = v;
      }
    }
    stageB(Bgp + (size_t)k0 * N13, N13, Bgs, bn, bq);
    stageB(Bup + (size_t)k0 * N13, N13, Bus, bn, bq);
    __syncthreads();
#pragma unroll
    for (int kk = 0; kk < 2; ++kk) {
      int koff = kk * 64 + lq * 16;
      bf16x8 a[4], bg[4], bu[4];
#pragma unroll
      for (int i = 0; i < 4; ++i) {
        int r = wr * 64 + i * 16 + l15;
        a[i] = *(const bf16x8*)&As[swz(r, koff) >> 1];
      }
#pragma unroll
      for (int j = 0; j < 4; ++j) {
        int n = wc * 64 + j * 16 + l15;
        bg[j] = *(const bf16x8*)&Bgs[swz(n, koff) >> 1];
        bu[j] = *(const bf16x8*)&Bus[swz(n, koff) >> 1];
      }
#pragma unroll
      for (int i = 0; i < 4; ++i)
#pragma unroll
        for (int j = 0; j < 4; ++j) {
          accg[i][j] = __builtin_amdgcn_mfma_f32_16x16x32_bf16(a[i], bg[j], accg[i][j], 0, 0, 0);
          accu[i][j] = __builtin_amdgcn_mfma_f32_16x16x32_bf16(a[i], bu[j], accu[i][j], 0, 0, 0);
        }
    }
    __syncthreads();
  }
  // epilogue: h = silu(g)*u -> bf16
#pragma unroll
  for (int i = 0; i < 4; ++i) {
#pragma unroll
    for (int r = 0; r < 4; ++r) {
      int rl = wr * 64 + i * 16 + lq * 4 + r;
      if (rl < rows) {
        size_t hrow = (size_t)(row0 + rl) * IMID;
#pragma unroll
        for (int j = 0; j < 4; ++j) {
          float g = accg[i][j][r], u = accu[i][j][r];
          float hv = g * u / (1.f + __expf(-g));
          hbuf[hrow + n0 + wc * 64 + j * 16 + l15] = (__bf16)hv;
        }
      }
    }
  }
}

// ---------------- grouped GEMM2: out += w_row * (h @ W2), atomic combine ----------------
__global__ __launch_bounds__(256, 2) void gemm2_kernel(const __bf16* __restrict__ hbuf,
                                                       const float* __restrict__ w2,
                                                       const float* __restrict__ sw2,
                                                       const int* __restrict__ row_token,
                                                       const float* __restrict__ row_w,
                                                       const int2* __restrict__ tiles,
                                                       float* __restrict__ out) {
  int2 td = tiles[blockIdx.x];
  int rows = td.y & 0xFFFF;
  if (rows == 0) return;
  int e = td.y >> 16, row0 = td.x;
  const float* W = (e < NE) ? (w2 + (size_t)e * (IMID * HD)) : sw2;  // [512][2048]
  int n0 = blockIdx.y * 128;

  __shared__ __bf16 As[128 * 64];
  __shared__ __bf16 Bs[128 * 64];

  int tid = threadIdx.x;
  int lane = tid & 63, wv = tid >> 6, wr = wv >> 1, wc = wv & 1;
  int l15 = lane & 15, lq = lane >> 4;

  int arow = tid >> 1, ahalf = tid & 1;
  int agrow = row0 + arow; if (agrow > NROWS - 1) agrow = NROWS - 1;
  const __bf16* Ap = hbuf + (size_t)agrow * IMID + ahalf * 32;

  int bn = lane * 2, bq = wv;
  const float* Bp = W + n0 + bn;

  f32x4 acc[4][4];
#pragma unroll
  for (int i = 0; i < 4; ++i)
#pragma unroll
    for (int j = 0; j < 4; ++j) acc[i][j] = (f32x4)(0.f);

  for (int k0 = 0; k0 < IMID; k0 += 64) {
    { // stage A (already bf16, contiguous)
      const bf16x8* src = (const bf16x8*)(Ap + k0);
#pragma unroll
      for (int i = 0; i < 4; ++i)
        *(bf16x8*)&As[swz(arow, ahalf * 64 + i * 16) >> 1] = src[i];
    }
    stageB(Bp + (size_t)k0 * HD, HD, Bs, bn, bq);
    __syncthreads();
#pragma unroll
    for (int kk = 0; kk < 2; ++kk) {
      int koff = kk * 64 + lq * 16;
      bf16x8 a[4], b[4];
#pragma unroll
      for (int i = 0; i < 4; ++i) {
        int r = wr * 64 + i * 16 + l15;
        a[i] = *(const bf16x8*)&As[swz(r, koff) >> 1];
      }
#pragma unroll
      for (int j = 0; j < 4; ++j) {
        int n = wc * 64 + j * 16 + l15;
        b[j] = *(const bf16x8*)&Bs[swz(n, koff) >> 1];
      }
#pragma unroll
      for (int i = 0; i < 4; ++i)
#pragma unroll
        for (int j = 0; j < 4; ++j)
          acc[i][j] = __builtin_amdgcn_mfma_f32_16x16x32_bf16(a[i], b[j], acc[i][j], 0, 0, 0);
    }
    __syncthreads();
  }
  // epilogue: weighted atomic combine into out
#pragma unroll
  for (int i = 0; i < 4; ++i) {
#pragma unroll
    for (int r = 0; r < 4; ++r) {
      int rl = wr * 64 + i * 16 + lq * 4 + r;
      if (rl < rows) {
        int gr = row0 + rl;
        int tok = row_token[gr];
        float wgt = row_w[gr];
        float* orow = out + (size_t)tok * HD + n0 + wc * 64;
#pragma unroll
        for (int j = 0; j < 4; ++j)
          atomicAdd(&orow[j * 16 + l15], acc[i][j][r] * wgt);
      }
    }
  }
}

// ---------------- launch ---------------------------------------------------------------
extern "C" void kernel_launch(void* const* d_in, const int* in_sizes, int n_in,
                              void* d_out, int out_size, void* d_ws, size_t ws_size,
                              hipStream_t stream) {
  const float* hidden = (const float*)d_in[0];
  const float* gate_w = (const float*)d_in[1];
  const float* w13    = (const float*)d_in[2];
  const float* w2     = (const float*)d_in[3];
  const float* sw13   = (const float*)d_in[4];
  const float* sw2    = (const float*)d_in[5];
  float* out = (float*)d_out;

  char* ws = (char*)d_ws;
  size_t off = 0;
  __bf16* hbuf   = (__bf16*)(ws + off); off += (size_t)NROWS * IMID * 2;   // 37,748,736
  float* logits  = (float*)(ws + off);  off += (size_t)T_TOK * NE * 4;     //  1,048,576
  int*   topk_id = (int*)(ws + off);    off += (size_t)NPAIR * 4;
  float* pair_w  = (float*)(ws + off);  off += (size_t)NPAIR * 4;
  int*   row_tok = (int*)(ws + off);    off += (size_t)NROWS * 4;
  float* row_w   = (float*)(ws + off);  off += (size_t)NROWS * 4;
  int*   counts  = (int*)(ws + off);    off += 512;
  int*   curs    = (int*)(ws + off);    off += 512;
  int*   offs    = (int*)(ws + off);    off += 512;
  int2*  tiles   = (int2*)(ws + off);   off += MAXTILES * 8;
  // total ~39.4 MB of d_ws

  init_kernel<<<(T_TOK * HD / 4 + T_TOK * NE / 4) / 256, 256, 0, stream>>>(
      (float4*)out, (float4*)logits, counts, curs);
  logits_kernel<<<dim3(T_TOK / 64, HD / 256), 256, 0, stream>>>(hidden, gate_w, logits);
  top8_kernel<<<T_TOK / 4, 256, 0, stream>>>(logits, topk_id, pair_w, counts);
  scan_kernel<<<1, 64, 0, stream>>>(counts, offs, tiles);
  scatter_kernel<<<NROWS / 256, 256, 0, stream>>>(topk_id, pair_w, offs, curs, row_tok, row_w);
  gemm1_kernel<<<dim3(MAXTILES, 4), 256, 0, stream>>>(hidden, w13, sw13, row_tok, tiles, hbuf);
  gemm2_kernel<<<dim3(MAXTILES, 16), 256, 0, stream>>>(hbuf, w2, sw2, row_tok, row_w, tiles, out);
}

// Round 2
// 1047.113 us; speedup vs baseline: 1.1609x; 1.1609x over previous
//
#include <hip/hip_runtime.h>
#include <hip/hip_bf16.h>

// ---------------- problem constants ----------------
#define T_TOK 4096
#define HD    2048
#define NE    64
#define TOPK  8
#define IMID  512
#define N13   1024                 // 2*I
#define NPAIR (T_TOK*TOPK)         // 32768
#define NROWS (NPAIR + T_TOK)      // 36864 (routed pairs + shared rows)
#define MAXT2 208                  // >= sum ceil(cnt_e/256) worst case (207)
#define RSCALE 2.5f

typedef __attribute__((ext_vector_type(8))) __bf16 bf16x8;
typedef __attribute__((ext_vector_type(4))) __bf16 bf16x4;
typedef __attribute__((ext_vector_type(4))) float  f32x4;

// ---------------- init: zero out, logits, counters ----------------
__global__ __launch_bounds__(256) void init_kernel(float4* __restrict__ out4,
                                                   float4* __restrict__ lg4,
                                                   int* __restrict__ counts,
                                                   int* __restrict__ curs) {
  int gid = blockIdx.x * 256 + threadIdx.x;
  float4 z; z.x = z.y = z.z = z.w = 0.f;
  if (gid < (T_TOK * HD / 4)) out4[gid] = z;
  else                        lg4[gid - T_TOK * HD / 4] = z;
  if (gid < NE + 1) { counts[gid] = 0; curs[gid] = 0; }
}

// ---------------- router logits ----------------
__global__ __launch_bounds__(256) void logits_kernel(const float* __restrict__ hs,
                                                     const float* __restrict__ gw,
                                                     float* __restrict__ logits) {
  __shared__ float hsm[64][64];
  __shared__ float gwm[64][64];
  int tid = threadIdx.x;
  int tb = blockIdx.x * 64;
  int kbase = blockIdx.y * 256;
  int tok = tid & 63, kq = tid >> 6;
  int tq = (tid & 15) * 4, eq = (tid >> 4) * 4;
  float acc[4][4] = {};
  for (int c = 0; c < 4; ++c) {
    int kb = kbase + c * 64;
#pragma unroll
    for (int it = 0; it < 4; ++it) {
      int k4 = kq * 16 + it * 4;
      float4 f = *(const float4*)&hs[(size_t)(tb + tok) * HD + kb + k4];
      hsm[k4 + 0][tok] = f.x; hsm[k4 + 1][tok] = f.y;
      hsm[k4 + 2][tok] = f.z; hsm[k4 + 3][tok] = f.w;
      int q = tid + it * 256;
      int grow = q >> 4, gc = (q & 15) * 4;
      *(float4*)&gwm[grow][gc] = *(const float4*)&gw[(size_t)(kb + grow) * NE + gc];
    }
    __syncthreads();
#pragma unroll 8
    for (int k = 0; k < 64; ++k) {
      float4 g = *(const float4*)&gwm[k][eq];
      float h0 = hsm[k][tq + 0], h1 = hsm[k][tq + 1];
      float h2 = hsm[k][tq + 2], h3 = hsm[k][tq + 3];
      acc[0][0] += h0 * g.x; acc[0][1] += h0 * g.y; acc[0][2] += h0 * g.z; acc[0][3] += h0 * g.w;
      acc[1][0] += h1 * g.x; acc[1][1] += h1 * g.y; acc[1][2] += h1 * g.z; acc[1][3] += h1 * g.w;
      acc[2][0] += h2 * g.x; acc[2][1] += h2 * g.y; acc[2][2] += h2 * g.z; acc[2][3] += h2 * g.w;
      acc[3][0] += h3 * g.x; acc[3][1] += h3 * g.y; acc[3][2] += h3 * g.z; acc[3][3] += h3 * g.w;
    }
    __syncthreads();
  }
#pragma unroll
  for (int i = 0; i < 4; ++i)
#pragma unroll
    for (int j = 0; j < 4; ++j)
      atomicAdd(&logits[(size_t)(tb + tq + i) * NE + eq + j], acc[i][j]);
}

// ---------------- sigmoid + top-8 ----------------
__global__ __launch_bounds__(256) void top8_kernel(const float* __restrict__ logits,
                                                   int* __restrict__ topk_id,
                                                   float* __restrict__ pair_w,
                                                   int* __restrict__ counts) {
  int lane = threadIdx.x & 63;
  int t = blockIdx.x * 4 + (threadIdx.x >> 6);
  float v = logits[(size_t)t * NE + lane];
  float s = 1.f / (1.f + __expf(-v));
  float cur = s, ssum = 0.f;
  int myid = 0; float myw = 0.f;
  for (int k = 0; k < TOPK; ++k) {
    float bv = cur; int bi = lane;
#pragma unroll
    for (int off = 32; off >= 1; off >>= 1) {
      float ov = __shfl_xor(bv, off);
      int   oi = __shfl_xor(bi, off);
      if (ov > bv || (ov == bv && oi < bi)) { bv = ov; bi = oi; }
    }
    ssum += bv;
    if (lane == k) { myid = bi; myw = bv; }
    if (lane == bi) cur = -1.f;
  }
  if (lane < TOPK) {
    topk_id[(size_t)t * TOPK + lane] = myid;
    pair_w[(size_t)t * TOPK + lane] = myw / ssum * RSCALE;
    atomicAdd(&counts[myid], 1);
  }
}

// ---------------- scan: offsets + 256-row tile table ----------------
__global__ void scan_kernel(int* __restrict__ counts, int* __restrict__ offs,
                            int2* __restrict__ tiles) {
  if (threadIdx.x != 0) return;
  counts[NE] = T_TOK;
  int off = 0, tix = 0;
  for (int e = 0; e <= NE; ++e) {
    offs[e] = off;
    int c = counts[e];
    int nt = (c + 255) >> 8;
    for (int i = 0; i < nt; ++i) {
      int rr = c - i * 256; if (rr > 256) rr = 256;
      tiles[tix++] = make_int2(off + i * 256, (e << 16) | rr);
    }
    off += c;
  }
  for (; tix < MAXT2; ++tix) tiles[tix] = make_int2(0, 0);
}

// ---------------- scatter pairs -> compact per-expert rows ----------------
__global__ __launch_bounds__(256) void scatter_kernel(const int* __restrict__ topk_id,
                                                      const float* __restrict__ pair_w,
                                                      const int* __restrict__ offs,
                                                      int* __restrict__ curs,
                                                      int* __restrict__ row_token,
                                                      float* __restrict__ row_w) {
  int p = blockIdx.x * 256 + threadIdx.x;
  int t, e; float w;
  if (p < NPAIR) { t = p >> 3; e = topk_id[p]; w = pair_w[p]; }
  else           { t = p - NPAIR; e = NE;     w = 1.0f; }
  int dst = offs[e] + atomicAdd(&curs[e], 1);
  row_token[dst] = t;
  row_w[dst] = w;
}

// ---------------- helpers ----------------
__device__ __forceinline__ int swz(int row, int kbyte) {     // [row][64 bf16 = 128B]
  return row * 128 + (kbyte ^ ((row & 7) << 4));
}
__device__ __forceinline__ void barrier_lgkm() {
  asm volatile("s_waitcnt lgkmcnt(0)" ::: "memory");
  __builtin_amdgcn_s_barrier();
  __builtin_amdgcn_sched_barrier(0);
}
// store 8 fp32 (2 float4) -> bf16x8 at swizzled [arow][kbyte..+16)
__device__ __forceinline__ void store_a8(__bf16* As, int arow, int kbyte, float4 f0, float4 f1) {
  bf16x8 v = { (__bf16)f0.x, (__bf16)f0.y, (__bf16)f0.z, (__bf16)f0.w,
               (__bf16)f1.x, (__bf16)f1.y, (__bf16)f1.z, (__bf16)f1.w };
  *(bf16x8*)&As[swz(arow, kbyte) >> 1] = v;
}
// transpose 4 k-rows x 2 cols of fp32 -> two bf16x4 column slivers
__device__ __forceinline__ void store_b4(__bf16* Bs, int c2, int kbyte, const float2* p) {
  bf16x4 c0 = { (__bf16)p[0].x, (__bf16)p[1].x, (__bf16)p[2].x, (__bf16)p[3].x };
  bf16x4 c1 = { (__bf16)p[0].y, (__bf16)p[1].y, (__bf16)p[2].y, (__bf16)p[3].y };
  *(bf16x4*)&Bs[swz(c2,     kbyte) >> 1] = c0;
  *(bf16x4*)&Bs[swz(c2 + 1, kbyte) >> 1] = c1;
}
// transpose 8 k-rows x 2 cols of fp32 -> two bf16x8 column slivers
__device__ __forceinline__ void store_b8(__bf16* Bs, int c2, int kbyte, const float2* p) {
  bf16x8 c0 = { (__bf16)p[0].x, (__bf16)p[1].x, (__bf16)p[2].x, (__bf16)p[3].x,
                (__bf16)p[4].x, (__bf16)p[5].x, (__bf16)p[6].x, (__bf16)p[7].x };
  bf16x8 c1 = { (__bf16)p[0].y, (__bf16)p[1].y, (__bf16)p[2].y, (__bf16)p[3].y,
                (__bf16)p[4].y, (__bf16)p[5].y, (__bf16)p[6].y, (__bf16)p[7].y };
  *(bf16x8*)&Bs[swz(c2,     kbyte) >> 1] = c0;
  *(bf16x8*)&Bs[swz(c2 + 1, kbyte) >> 1] = c1;
}

// ---------------- grouped GEMM1: BM=256, BN=64(g)+64(u), BK=64, dbuf+prefetch ----------
__global__ __launch_bounds__(512, 1) void gemm1_kernel(const float* __restrict__ hidden,
                                                       const float* __restrict__ w13,
                                                       const float* __restrict__ sw13,
                                                       const int* __restrict__ row_token,
                                                       const int2* __restrict__ tiles,
                                                       __bf16* __restrict__ hbuf) {
  int2 td = tiles[blockIdx.x];
  int rows = td.y & 0xFFFF;
  if (rows == 0) return;
  int e = td.y >> 16, row0 = td.x;
  const float* W = (e < NE) ? (w13 + (size_t)e * (HD * N13)) : sw13;  // [2048][1024]
  int n0 = blockIdx.y * 64;                                           // gate col base; up at +512

  __shared__ __bf16 As[2][256 * 64];   // 64 KB
  __shared__ __bf16 Bgs[2][64 * 64];   // 16 KB
  __shared__ __bf16 Bus[2][64 * 64];   // 16 KB

  int tid = threadIdx.x;
  int lane = tid & 63, wv = tid >> 6;
  int l15 = lane & 15, lq = lane >> 4;

  // A gather: 2 threads/row, 32 floats each per k-step
  int arow = tid >> 1, ahalf = tid & 1;
  int grow = row0 + arow; if (grow >= NROWS) grow = NROWS - 1;
  const float* Ap = hidden + (size_t)row_token[grow] * HD + ahalf * 32;
  // B: col-pair + 4 k-rows per thread per matrix
  int c2 = (tid & 31) * 2, kq = tid >> 5;        // kq in [0,16)
  const float* Bg0 = W + (size_t)(kq * 4) * N13 + n0 + c2;
  const float* Bu0 = W + (size_t)(kq * 4) * N13 + 512 + n0 + c2;

  float4 pa[8]; float2 pg[4], pu[4];
#pragma unroll
  for (int i = 0; i < 8; ++i) pa[i] = *(const float4*)(Ap + i * 4);
#pragma unroll
  for (int r = 0; r < 4; ++r) {
    pg[r] = *(const float2*)(Bg0 + (size_t)r * N13);
    pu[r] = *(const float2*)(Bu0 + (size_t)r * N13);
  }
#pragma unroll
  for (int i = 0; i < 4; ++i) store_a8(As[0], arow, ahalf * 64 + i * 16, pa[2 * i], pa[2 * i + 1]);
  store_b4(Bgs[0], c2, kq * 8, pg);
  store_b4(Bus[0], c2, kq * 8, pu);

  f32x4 accg[2][4], accu[2][4];
#pragma unroll
  for (int i = 0; i < 2; ++i)
#pragma unroll
    for (int j = 0; j < 4; ++j) { accg[i][j] = (f32x4)(0.f); accu[i][j] = (f32x4)(0.f); }

  for (int s = 0; s < 32; ++s) {
    int cur = s & 1;
    if (s + 1 < 32) {   // issue next-step global loads (latency hides under MFMA)
      const float* Ap2 = Ap + (s + 1) * 64;
      const float* Bg2 = Bg0 + (size_t)(s + 1) * 64 * N13;
      const float* Bu2 = Bu0 + (size_t)(s + 1) * 64 * N13;
#pragma unroll
      for (int i = 0; i < 8; ++i) pa[i] = *(const float4*)(Ap2 + i * 4);
#pragma unroll
      for (int r = 0; r < 4; ++r) {
        pg[r] = *(const float2*)(Bg2 + (size_t)r * N13);
        pu[r] = *(const float2*)(Bu2 + (size_t)r * N13);
      }
    }
    barrier_lgkm();   // buf[cur] writes (prev iter) visible to all
#pragma unroll
    for (int kk = 0; kk < 2; ++kk) {
      int koff = kk * 64 + lq * 16;
      bf16x8 a[2], bg[4], bu[4];
#pragma unroll
      for (int i = 0; i < 2; ++i)
        a[i] = *(const bf16x8*)&As[cur][swz(wv * 32 + i * 16 + l15, koff) >> 1];
#pragma unroll
      for (int j = 0; j < 4; ++j) {
        bg[j] = *(const bf16x8*)&Bgs[cur][swz(j * 16 + l15, koff) >> 1];
        bu[j] = *(const bf16x8*)&Bus[cur][swz(j * 16 + l15, koff) >> 1];
      }
#pragma unroll
      for (int i = 0; i < 2; ++i)
#pragma unroll
        for (int j = 0; j < 4; ++j) {
          accg[i][j] = __builtin_amdgcn_mfma_f32_16x16x32_bf16(a[i], bg[j], accg[i][j], 0, 0, 0);
          accu[i][j] = __builtin_amdgcn_mfma_f32_16x16x32_bf16(a[i], bu[j], accu[i][j], 0, 0, 0);
        }
    }
    if (s + 1 < 32) {   // cvt (waits vmcnt) + write to other buffer
      int nxt = cur ^ 1;
#pragma unroll
      for (int i = 0; i < 4; ++i) store_a8(As[nxt], arow, ahalf * 64 + i * 16, pa[2 * i], pa[2 * i + 1]);
      store_b4(Bgs[nxt], c2, kq * 8, pg);
      store_b4(Bus[nxt], c2, kq * 8, pu);
    }
  }
  // epilogue: h = silu(g)*u -> bf16 (wave owns rows [wv*32, +32), cols [n0, n0+64))
#pragma unroll
  for (int mi = 0; mi < 2; ++mi) {
#pragma unroll
    for (int r = 0; r < 4; ++r) {
      int rl = wv * 32 + mi * 16 + lq * 4 + r;
      if (rl < rows) {
        size_t hrow = (size_t)(row0 + rl) * IMID;
#pragma unroll
        for (int j = 0; j < 4; ++j) {
          float g = accg[mi][j][r], u = accu[mi][j][r];
          float hv = g * u / (1.f + __expf(-g));
          hbuf[hrow + n0 + j * 16 + l15] = (__bf16)hv;
        }
      }
    }
  }
}

// ---------------- grouped GEMM2: BM=256, BN=128, BK=64, dbuf+prefetch, atomic combine ----
__global__ __launch_bounds__(512, 1) void gemm2_kernel(const __bf16* __restrict__ hbuf,
                                                       const float* __restrict__ w2,
                                                       const float* __restrict__ sw2,
                                                       const int* __restrict__ row_token,
                                                       const float* __restrict__ row_w,
                                                       const int2* __restrict__ tiles,
                                                       float* __restrict__ out) {
  int2 td = tiles[blockIdx.x];
  int rows = td.y & 0xFFFF;
  if (rows == 0) return;
  int e = td.y >> 16, row0 = td.x;
  const float* W = (e < NE) ? (w2 + (size_t)e * (IMID * HD)) : sw2;   // [512][2048]
  int n0 = blockIdx.y * 128;

  __shared__ __bf16 As[2][256 * 64];   // 64 KB
  __shared__ __bf16 Bs[2][128 * 64];   // 32 KB

  int tid = threadIdx.x;
  int lane = tid & 63, wv = tid >> 6, wr = wv >> 1, wc = wv & 1;
  int l15 = lane & 15, lq = lane >> 4;

  int arow = tid >> 1, ahalf = tid & 1;
  int agrow = row0 + arow; if (agrow >= NROWS) agrow = NROWS - 1;
  const __bf16* Ap = hbuf + (size_t)agrow * IMID + ahalf * 32;

  int c2 = (tid & 63) * 2, kq = tid >> 6;        // kq in [0,8), 8 k-rows each
  const float* Bp0 = W + (size_t)(kq * 8) * HD + n0 + c2;

  bf16x8 pa[4]; float2 pb[8];
#pragma unroll
  for (int i = 0; i < 4; ++i) pa[i] = *(const bf16x8*)(Ap + i * 8);
#pragma unroll
  for (int r = 0; r < 8; ++r) pb[r] = *(const float2*)(Bp0 + (size_t)r * HD);
#pragma unroll
  for (int i = 0; i < 4; ++i) *(bf16x8*)&As[0][swz(arow, ahalf * 64 + i * 16) >> 1] = pa[i];
  store_b8(Bs[0], c2, kq * 16, pb);

  f32x4 acc[4][4];
#pragma unroll
  for (int i = 0; i < 4; ++i)
#pragma unroll
    for (int j = 0; j < 4; ++j) acc[i][j] = (f32x4)(0.f);

  for (int s = 0; s < 8; ++s) {
    int cur = s & 1;
    if (s + 1 < 8) {
      const __bf16* Ap2 = Ap + (s + 1) * 64;
      const float* Bp2 = Bp0 + (size_t)(s + 1) * 64 * HD;
#pragma unroll
      for (int i = 0; i < 4; ++i) pa[i] = *(const bf16x8*)(Ap2 + i * 8);
#pragma unroll
      for (int r = 0; r < 8; ++r) pb[r] = *(const float2*)(Bp2 + (size_t)r * HD);
    }
    barrier_lgkm();
#pragma unroll
    for (int kk = 0; kk < 2; ++kk) {
      int koff = kk * 64 + lq * 16;
      bf16x8 a[4], b[4];
#pragma unroll
      for (int i = 0; i < 4; ++i)
        a[i] = *(const bf16x8*)&As[cur][swz(wr * 64 + i * 16 + l15, koff) >> 1];
#pragma unroll
      for (int j = 0; j < 4; ++j)
        b[j] = *(const bf16x8*)&Bs[cur][swz(wc * 64 + j * 16 + l15, koff) >> 1];
#pragma unroll
      for (int i = 0; i < 4; ++i)
#pragma unroll
        for (int j = 0; j < 4; ++j)
          acc[i][j] = __builtin_amdgcn_mfma_f32_16x16x32_bf16(a[i], b[j], acc[i][j], 0, 0, 0);
    }
    if (s + 1 < 8) {
      int nxt = cur ^ 1;
#pragma unroll
      for (int i = 0; i < 4; ++i) *(bf16x8*)&As[nxt][swz(arow, ahalf * 64 + i * 16) >> 1] = pa[i];
      store_b8(Bs[nxt], c2, kq * 16, pb);
    }
  }
  // epilogue: weighted atomic combine
#pragma unroll
  for (int i = 0; i < 4; ++i) {
#pragma unroll
    for (int r = 0; r < 4; ++r) {
      int rl = wr * 64 + i * 16 + lq * 4 + r;
      if (rl < rows) {
        int gr = row0 + rl;
        int tok = row_token[gr];
        float wgt = row_w[gr];
        float* orow = out + (size_t)tok * HD + n0 + wc * 64;
#pragma unroll
        for (int j = 0; j < 4; ++j)
          atomicAdd(&orow[j * 16 + l15], acc[i][j][r] * wgt);
      }
    }
  }
}

// ---------------- launch ----------------
extern "C" void kernel_launch(void* const* d_in, const int* in_sizes, int n_in,
                              void* d_out, int out_size, void* d_ws, size_t ws_size,
                              hipStream_t stream) {
  const float* hidden = (const float*)d_in[0];
  const float* gate_w = (const float*)d_in[1];
  const float* w13    = (const float*)d_in[2];
  const float* w2     = (const float*)d_in[3];
  const float* sw13   = (const float*)d_in[4];
  const float* sw2    = (const float*)d_in[5];
  float* out = (float*)d_out;

  char* ws = (char*)d_ws;
  size_t off = 0;
  __bf16* hbuf   = (__bf16*)(ws + off); off += (size_t)NROWS * IMID * 2;
  float* logits  = (float*)(ws + off);  off += (size_t)T_TOK * NE * 4;
  int*   topk_id = (int*)(ws + off);    off += (size_t)NPAIR * 4;
  float* pair_w  = (float*)(ws + off);  off += (size_t)NPAIR * 4;
  int*   row_tok = (int*)(ws + off);    off += (size_t)NROWS * 4;
  float* row_w   = (float*)(ws + off);  off += (size_t)NROWS * 4;
  int*   counts  = (int*)(ws + off);    off += 512;
  int*   curs    = (int*)(ws + off);    off += 512;
  int*   offs    = (int*)(ws + off);    off += 512;
  int2*  tiles   = (int2*)(ws + off);   off += MAXT2 * 8;

  init_kernel<<<(T_TOK * HD / 4 + T_TOK * NE / 4) / 256, 256, 0, stream>>>(
      (float4*)out, (float4*)logits, counts, curs);
  logits_kernel<<<dim3(T_TOK / 64, HD / 256), 256, 0, stream>>>(hidden, gate_w, logits);
  top8_kernel<<<T_TOK / 4, 256, 0, stream>>>(logits, topk_id, pair_w, counts);
  scan_kernel<<<1, 64, 0, stream>>>(counts, offs, tiles);
  scatter_kernel<<<NROWS / 256, 256, 0, stream>>>(topk_id, pair_w, offs, curs, row_tok, row_w);
  gemm1_kernel<<<dim3(MAXT2, 8), 512, 0, stream>>>(hidden, w13, sw13, row_tok, tiles, hbuf);
  gemm2_kernel<<<dim3(MAXT2, 16), 512, 0, stream>>>(hbuf, w2, sw2, row_tok, row_w, tiles, out);
}